// Round 17
// baseline (275.141 us; speedup 1.0000x reference)
//
#include <hip/hip_runtime.h>
#include <hip/hip_bf16.h>
#include <cstdint>
#include <cstddef>

#define KDIM 4096   // IN_F
#define NDIM 4096   // OUT_F
#define NG 32       // groups per row
#define GRP 128     // group size

typedef __attribute__((ext_vector_type(8))) short short8;
typedef __attribute__((ext_vector_type(8))) __bf16 bf16x8;
typedef __attribute__((ext_vector_type(4))) float f32x4;
typedef __attribute__((ext_vector_type(4))) int i32x4;

__device__ __forceinline__ unsigned short bf16_rne(float f) {
    unsigned int u = __builtin_bit_cast(unsigned int, f);
    u += 0x7fffu + ((u >> 16) & 1u);
    return (unsigned short)(u >> 16);
}

__device__ __forceinline__ void gload16(const void* g, void* l) {
    __builtin_amdgcn_global_load_lds(
        (const __attribute__((address_space(1))) unsigned int*)g,
        (__attribute__((address_space(3))) unsigned int*)l,
        16, 0, 0);
}

// ============ prep (unchanged from R16, proven): x->i8/row + group sums; W->i8; z->bf16; s->st[g][N]
__global__ void prep_kernel(const float* __restrict__ x, const int* __restrict__ wp,
                            const float* __restrict__ scales, const float* __restrict__ zeros,
                            signed char* __restrict__ xq, signed char* __restrict__ wq,
                            unsigned short* __restrict__ Sb, float* __restrict__ arow,
                            unsigned short* __restrict__ zb, float* __restrict__ st,
                            int nbx, int nbw) {
    const int b = blockIdx.x;
    const int t = threadIdx.x;
    if (b < nbx) {
        __shared__ float red[256];
        __shared__ float gs[256];
        const float4* xr = (const float4*)(x + (size_t)b * KDIM);
        float4 v[4];
        float mx = 0.f, sum = 0.f;
#pragma unroll
        for (int j = 0; j < 4; ++j) {
            v[j] = xr[t * 4 + j];
            mx = fmaxf(mx, fmaxf(fmaxf(fabsf(v[j].x), fabsf(v[j].y)),
                                 fmaxf(fabsf(v[j].z), fabsf(v[j].w))));
            sum += v[j].x + v[j].y + v[j].z + v[j].w;
        }
        red[t] = mx; gs[t] = sum;
        __syncthreads();
        for (int s = 128; s > 0; s >>= 1) {
            if (t < s) red[t] = fmaxf(red[t], red[t + s]);
            __syncthreads();
        }
        const float amax = red[0];
        const float inv = (amax > 0.f) ? 127.f / amax : 0.f;
        union { signed char c[16]; i32x4 q; } o;
#pragma unroll
        for (int j = 0; j < 4; ++j) {
            o.c[4 * j + 0] = (signed char)(int)rintf(v[j].x * inv);
            o.c[4 * j + 1] = (signed char)(int)rintf(v[j].y * inv);
            o.c[4 * j + 2] = (signed char)(int)rintf(v[j].z * inv);
            o.c[4 * j + 3] = (signed char)(int)rintf(v[j].w * inv);
        }
        ((i32x4*)(xq + (size_t)b * KDIM))[t] = o.q;
        if (t < NG) {
            float s8 = 0.f;
#pragma unroll
            for (int j = 0; j < 8; ++j) s8 += gs[t * 8 + j];
            Sb[(size_t)b * NG + t] = bf16_rne(s8);
        }
        if (t == 0) arow[b] = amax * (1.f / 127.f);
    } else if (b < nbx + nbw) {
        long i = (long)(b - nbx) * 256 + t;
        int4 p = ((const int4*)wp)[i];
        union { signed char c[16]; i32x4 q; } o;
#pragma unroll
        for (int j = 0; j < 4; ++j) {
            o.c[j]      = (signed char)((p.x >> (2 * j)) & 3);
            o.c[4 + j]  = (signed char)((p.y >> (2 * j)) & 3);
            o.c[8 + j]  = (signed char)((p.z >> (2 * j)) & 3);
            o.c[12 + j] = (signed char)((p.w >> (2 * j)) & 3);
        }
        ((i32x4*)wq)[i] = o.q;
    } else {
        long i = (long)(b - nbx - nbw) * 256 + t;
        int oo = (int)(i >> 5), g = (int)(i & 31);
        zb[i] = bf16_rne(zeros[i]);
        st[(size_t)g * NDIM + oo] = scales[i];
    }
}

// ============ i8 GEMM (R17): 256x128 tile, BK=64, 2 blocks/CU ============
// Per wave (4Mx2N of 8 waves): 64x64 out, acc f32[4][4]x4 = 64 VGPR ->
// total live ~120 <= 128 => __launch_bounds__(512,4): 4 waves/SIMD =
// 2 co-resident blocks/CU (LDS 2x25KB). One block's MFMA overlaps the
// other's LDS/VALU/barrier epochs (m114) — the serialization R7-R16 hit.
// SYNC LEDGER (free-run ring, proven R6/R16 shape, 4 gloads/wave/tile):
//  {reads (8 b128 + 4 b32) -> 16 MFMA + rescale (data-dep)}; B1;
//  stage t+2 (A:2,B:1,S:1); vmcnt(4) drains t+1's 4; B2 => t+1 resident.
//  Tail: t2 clamped to t => byte-idempotent restage. Post-loop vmcnt(0).
// 64B-ROW SWIZZLE (new derivation; R9's failure explained): HW serves 8
//  consecutive lanes/cycle; each must hit 8 distinct 128B bank-groups.
//  group(addr) = (4*(r&1) + seg') mod 8. seg' = lk4 ^ ((r>>1)&3) makes
//  lanes l..l+7 (rows r..r+7, lk4 fixed) hit {4*(r&1) + distinct 0..3} = all 8.
//  (R9's seg'=lk4^(r&3) collided rows {0,4},{1,5}... -> 2-way, 3.4e7 conflicts.)
//  Store side: linear DMA dest + pre-swizzled source seg (tid&3)^((tid>>3)&3)
//  ((srow>>1)&3, srow=tid>>2); row+128 preserves (r>>1)&3. Both-sides ✓.
// i8 frag layout (proven R16): lane(lr,lk4) reads 16B at k=16*lk4 of row lr.

#define SMBUF 25600   // A 16384 | B 8192 | S 1024

#define WGBAR \
    __builtin_amdgcn_sched_barrier(0); \
    __builtin_amdgcn_s_barrier(); \
    __builtin_amdgcn_sched_barrier(0);

#define VMCNT(N) \
    __builtin_amdgcn_sched_barrier(0); \
    asm volatile("s_waitcnt vmcnt(" #N ")" ::: "memory"); \
    __builtin_amdgcn_sched_barrier(0);

__global__ __launch_bounds__(512, 4) void gemm_i8(const signed char* __restrict__ A,
                                                  const signed char* __restrict__ B,
                                                  const unsigned short* __restrict__ Sb,
                                                  const float* __restrict__ arow,
                                                  const unsigned short* __restrict__ zb,
                                                  const float* __restrict__ st,
                                                  const float* __restrict__ bias,
                                                  float* __restrict__ C) {
    __shared__ __align__(16) signed char sm[2 * SMBUF];   // 50 KiB

    const int tid = threadIdx.x;
    const int w64 = tid >> 6;
    const int lane = tid & 63;

    // T1: bijective XCD swizzle (gridDim.x % 8 == 0)
    const int nwg = gridDim.x;
    const int chunk = nwg >> 3;
    const int s_id = (blockIdx.x & 7) * chunk + (blockIdx.x >> 3);
    const int nm = nwg >> 5;              // M tiles (N tiles = 32)
    const int bm = s_id % nm;
    const int bn = s_id / nm;
    const int row0 = bm * 256;
    const int col0 = bn * 128;

    const int wr = w64 >> 1;              // 0..3 (M: 64 rows)
    const int wc = w64 & 1;               // 0..1 (N: 64 cols)

    // ---- stage addressing: srow = tid>>2 (0..127), seg = tid&3, pre-swizzled src
    const int srow = tid >> 2;
    const int sswz = 16 * ((tid & 3) ^ ((tid >> 3) & 3));   // seg ^ ((srow>>1)&3)
    const signed char* srcA = A + (size_t)(row0 + srow) * KDIM + sswz;
    const signed char* srcB = B + (size_t)(col0 + srow) * KDIM + sswz;
    const float* srcS = st + col0 + ((lane & 31) << 2);     // lanes 32-63 duplicate (dead region)

    // ---- frag addressing: row r, seg' = lk4 ^ ((r>>1)&3) == lk4 ^ ((lr>>1)&3)
    const int lr = lane & 15;
    const int lk4 = lane >> 4;
    const int sw = 16 * (lk4 ^ ((lr >> 1) & 3));
    const int aBase = (wr * 64 + lr) * 64;          // + m*1024 (16 rows x 64B)
    const int bBase = 16384 + (wc * 64 + lr) * 64;  // + n*1024

    f32x4 acc[4][4] = {};

    auto stage = [&](int tile, int db) {
        const signed char* gA = srcA + (size_t)tile * 64;
        const signed char* gB = srcB + (size_t)tile * 64;
        signed char* lA = &sm[db * SMBUF + w64 * 1024];
        signed char* lB = &sm[db * SMBUF + 16384 + w64 * 1024];
        gload16(gA, lA);                                   // A rows 0-127
        gload16(gA + (size_t)128 * KDIM, lA + 8192);       // A rows 128-255
        gload16(gB, lB);                                   // B rows 0-127
        gload16(srcS + (size_t)(tile >> 1) * NDIM, &sm[db * SMBUF + 24576]);  // S (idempotent x8 waves)
    };

    const int NT = KDIM / 64;   // 64 K-tiles; group g = t>>1

    // ---- prologue: tile0 -> buf0, tile1 -> buf1 (4 gloads each)
    stage(0, 0);
    stage(1, 1);
    VMCNT(4)                    // tile0's 4 landed (tile1 in flight)
    WGBAR

    for (int t = 0; t < NT; ++t) {
        const int d = t & 1;
        const int dOff = d * SMBUF;
        const int t2 = (t + 2 < NT) ? t + 2 : t;   // clamped tail: byte-idempotent restage

        i32x4 bQ[4];
        float s4[4];
#pragma unroll
        for (int n = 0; n < 4; ++n)
            bQ[n] = *(const i32x4*)&sm[dOff + bBase + n * 1024 + sw];
#pragma unroll
        for (int n = 0; n < 4; ++n)
            s4[n] = *(const float*)&sm[dOff + 24576 + (wc * 64 + n * 16 + lr) * 4];

        __builtin_amdgcn_s_setprio(1);
        i32x4 aF[4];
#pragma unroll
        for (int m = 0; m < 4; ++m)
            aF[m] = *(const i32x4*)&sm[dOff + aBase + m * 1024 + sw];
#pragma unroll
        for (int m = 0; m < 4; ++m)
#pragma unroll
            for (int n = 0; n < 4; ++n) {
                i32x4 ai = __builtin_amdgcn_mfma_i32_16x16x64_i8(
                    aF[m], bQ[n], (i32x4){0, 0, 0, 0}, 0, 0, 0);
#pragma unroll
                for (int r = 0; r < 4; ++r)
                    acc[m][n][r] += s4[n] * (float)ai[r];
            }
        __builtin_amdgcn_s_setprio(0);

        // ---- B1: all LDS reads of tile t consumed (data-dep) -> buf d free ----
        WGBAR
        stage(t2, d);
        VMCNT(4)                 // drains tile t+1's 4 loads
        WGBAR                    // B2: tile t+1 resident cross-wave
    }

    // no LDS-DMA / dangling reads may outlive the loop
    __builtin_amdgcn_sched_barrier(0);
    asm volatile("s_waitcnt vmcnt(0) lgkmcnt(0)" ::: "memory");
    __builtin_amdgcn_sched_barrier(0);

    // ---- epilogue: acc *= a_row; z-term via bf16 MFMA (C-in); +bias; store
    float am[4][4];
#pragma unroll
    for (int m = 0; m < 4; ++m)
#pragma unroll
        for (int r = 0; r < 4; ++r)
            am[m][r] = arow[row0 + wr * 64 + m * 16 + lk4 * 4 + r];
#pragma unroll
    for (int m = 0; m < 4; ++m)
#pragma unroll
        for (int n = 0; n < 4; ++n)
#pragma unroll
            for (int r = 0; r < 4; ++r)
                acc[m][n][r] *= am[m][r];

    short8 aS[4], bZ[4];
#pragma unroll
    for (int m = 0; m < 4; ++m)
        aS[m] = *(const short8*)&Sb[(size_t)(row0 + wr * 64 + m * 16 + lr) * NG + lk4 * 8];
#pragma unroll
    for (int n = 0; n < 4; ++n)
        bZ[n] = *(const short8*)&zb[(size_t)(col0 + wc * 64 + n * 16 + lr) * NG + lk4 * 8];
#pragma unroll
    for (int m = 0; m < 4; ++m)
#pragma unroll
        for (int n = 0; n < 4; ++n)
            acc[m][n] = __builtin_amdgcn_mfma_f32_16x16x32_bf16(
                __builtin_bit_cast(bf16x8, aS[m]), __builtin_bit_cast(bf16x8, bZ[n]),
                acc[m][n], 0, 0, 0);

    // C/D layout col=lane&15, row=(lane>>4)*4+r (verified)
#pragma unroll
    for (int m = 0; m < 4; ++m) {
#pragma unroll
        for (int n = 0; n < 4; ++n) {
            int col = col0 + wc * 64 + n * 16 + lr;
            float bz = bias[col];
#pragma unroll
            for (int r = 0; r < 4; ++r) {
                int row = row0 + wr * 64 + m * 16 + lk4 * 4 + r;
                C[(size_t)row * NDIM + col] = acc[m][n][r] + bz;
            }
        }
    }
}

// ---------------- emergency fallback (ws too small / odd shape): exact fp32 ----------------
__global__ void fallback_kernel(const float* __restrict__ x, const int* __restrict__ wp,
                                const float* __restrict__ scales, const float* __restrict__ zeros,
                                const float* __restrict__ bias, float* __restrict__ out) {
    int o = blockIdx.x * 256 + threadIdx.x;
    int m = blockIdx.y;
    __shared__ float xs[KDIM];
    for (int i = threadIdx.x; i < KDIM; i += 256) xs[i] = x[(size_t)m * KDIM + i];
    __syncthreads();
    float acc = 0.f;
    for (int g = 0; g < 32; ++g) {
        float s = scales[o * 32 + g], z = zeros[o * 32 + g];
        float aq = 0.f, ax = 0.f;
        for (int j = 0; j < 32; ++j) {
            int p = wp[o * 1024 + g * 32 + j];
            int kb = g * 128 + j * 4;
#pragma unroll
            for (int q = 0; q < 4; ++q) {
                float xv = xs[kb + q];
                aq += xv * (float)((p >> (2 * q)) & 3);
                ax += xv;
            }
        }
        acc += s * aq + z * ax;
    }
    out[(size_t)m * NDIM + o] = acc + bias[o];
}

extern "C" void kernel_launch(void* const* d_in, const int* in_sizes, int n_in,
                              void* d_out, int out_size, void* d_ws, size_t ws_size,
                              hipStream_t stream) {
    const float* x      = (const float*)d_in[0];
    const int*   wp     = (const int*)d_in[1];
    const float* scales = (const float*)d_in[2];
    const float* zeros  = (const float*)d_in[3];
    const float* bias   = (const float*)d_in[4];
    float* out = (float*)d_out;

    const long M = (long)in_sizes[0] / KDIM;            // 8192
    const long PACKED = (long)in_sizes[1];              // 4194304

    // ws layout (bytes)
    const size_t xq_off = 0;
    const size_t wq_off = (size_t)M * KDIM;
    const size_t Sb_off = wq_off + (size_t)NDIM * KDIM;
    const size_t ar_off = Sb_off + (size_t)M * NG * 2;
    const size_t zb_off = ar_off + (size_t)M * 4;
    const size_t st_off = zb_off + (size_t)NDIM * NG * 2;
    const size_t need   = st_off + (size_t)NG * NDIM * 4;

    if (ws_size >= need && (M % 256) == 0) {
        signed char* xq = (signed char*)d_ws + xq_off;
        signed char* wq = (signed char*)d_ws + wq_off;
        unsigned short* Sb = (unsigned short*)((char*)d_ws + Sb_off);
        float* ar = (float*)((char*)d_ws + ar_off);
        unsigned short* zb = (unsigned short*)((char*)d_ws + zb_off);
        float* st = (float*)((char*)d_ws + st_off);

        int nbx = (int)M;                               // 8192 row blocks
        int nbw = (int)((NDIM * (long)KDIM / 16) / 256);// 4096 unpack blocks
        int nbz = (int)((NDIM * (long)NG) / 256);       // 512 z/st blocks
        prep_kernel<<<nbx + nbw + nbz, 256, 0, stream>>>(x, wp, scales, zeros,
                                                         xq, wq, Sb, ar, zb, st, nbx, nbw);
        int nwg = (int)(M / 256) * (NDIM / 128);        // 32*32 = 1024, %8==0
        gemm_i8<<<nwg, 512, 0, stream>>>(xq, wq, Sb, ar, zb, st, bias, out);
    } else {
        dim3 grid(NDIM / 256, M);
        fallback_kernel<<<grid, 256, 0, stream>>>(x, wp, scales, zeros, bias, out);
    }
}

// Round 18
// 238.204 us; speedup vs baseline: 1.1551x; 1.1551x over previous
//
#include <hip/hip_runtime.h>
#include <hip/hip_bf16.h>
#include <cstdint>
#include <cstddef>

#define KDIM 4096   // IN_F
#define NDIM 4096   // OUT_F
#define NG 32       // groups per row
#define GRP 128     // group size == BK

typedef __attribute__((ext_vector_type(8))) short short8;
typedef __attribute__((ext_vector_type(8))) __bf16 bf16x8;
typedef __attribute__((ext_vector_type(4))) float f32x4;
typedef __attribute__((ext_vector_type(4))) int i32x4;

__device__ __forceinline__ unsigned short bf16_rne(float f) {
    unsigned int u = __builtin_bit_cast(unsigned int, f);
    u += 0x7fffu + ((u >> 16) & 1u);
    return (unsigned short)(u >> 16);
}

__device__ __forceinline__ void gload16(const void* g, void* l) {
    __builtin_amdgcn_global_load_lds(
        (const __attribute__((address_space(1))) unsigned int*)g,
        (__attribute__((address_space(3))) unsigned int*)l,
        16, 0, 0);
}

// ============ prep (R16, proven): x->i8 per-row + group sums; W 2-bit->i8; z->bf16; scales->st[g][N]
__global__ void prep_kernel(const float* __restrict__ x, const int* __restrict__ wp,
                            const float* __restrict__ scales, const float* __restrict__ zeros,
                            signed char* __restrict__ xq, signed char* __restrict__ wq,
                            unsigned short* __restrict__ Sb, float* __restrict__ arow,
                            unsigned short* __restrict__ zb, float* __restrict__ st,
                            int nbx, int nbw) {
    const int b = blockIdx.x;
    const int t = threadIdx.x;
    if (b < nbx) {
        __shared__ float red[256];
        __shared__ float gs[256];
        const float4* xr = (const float4*)(x + (size_t)b * KDIM);
        float4 v[4];
        float mx = 0.f, sum = 0.f;
#pragma unroll
        for (int j = 0; j < 4; ++j) {
            v[j] = xr[t * 4 + j];
            mx = fmaxf(mx, fmaxf(fmaxf(fabsf(v[j].x), fabsf(v[j].y)),
                                 fmaxf(fabsf(v[j].z), fabsf(v[j].w))));
            sum += v[j].x + v[j].y + v[j].z + v[j].w;
        }
        red[t] = mx; gs[t] = sum;
        __syncthreads();
        for (int s = 128; s > 0; s >>= 1) {
            if (t < s) red[t] = fmaxf(red[t], red[t + s]);
            __syncthreads();
        }
        const float amax = red[0];
        const float inv = (amax > 0.f) ? 127.f / amax : 0.f;
        union { signed char c[16]; i32x4 q; } o;
#pragma unroll
        for (int j = 0; j < 4; ++j) {
            o.c[4 * j + 0] = (signed char)(int)rintf(v[j].x * inv);
            o.c[4 * j + 1] = (signed char)(int)rintf(v[j].y * inv);
            o.c[4 * j + 2] = (signed char)(int)rintf(v[j].z * inv);
            o.c[4 * j + 3] = (signed char)(int)rintf(v[j].w * inv);
        }
        ((i32x4*)(xq + (size_t)b * KDIM))[t] = o.q;
        if (t < NG) {   // thread t sums group t (8 sub-sums of 16)
            float s8 = 0.f;
#pragma unroll
            for (int j = 0; j < 8; ++j) s8 += gs[t * 8 + j];
            Sb[(size_t)b * NG + t] = bf16_rne(s8);
        }
        if (t == 0) arow[b] = amax * (1.f / 127.f);
    } else if (b < nbx + nbw) {
        long i = (long)(b - nbx) * 256 + t;   // 4 packed ints = 16 weights
        int4 p = ((const int4*)wp)[i];
        union { signed char c[16]; i32x4 q; } o;
#pragma unroll
        for (int j = 0; j < 4; ++j) {
            o.c[j]      = (signed char)((p.x >> (2 * j)) & 3);
            o.c[4 + j]  = (signed char)((p.y >> (2 * j)) & 3);
            o.c[8 + j]  = (signed char)((p.z >> (2 * j)) & 3);
            o.c[12 + j] = (signed char)((p.w >> (2 * j)) & 3);
        }
        ((i32x4*)wq)[i] = o.q;
    } else {
        long i = (long)(b - nbx - nbw) * 256 + t;   // one (o,g)
        int oo = (int)(i >> 5), g = (int)(i & 31);
        zb[i] = bf16_rne(zeros[i]);
        st[(size_t)g * NDIM + oo] = scales[i];
    }
}

// ============ i8 GEMM (R16, proven best: 216 µs): 256x256 tile, BK=128=GROUP, free-run ring
// acc_f32[m][n] += s[o,g] * i32mfma(qx, qw over group g); epilogue: *= a_row,
// += z-term via ONE bf16 16x16x32 MFMA tile (C-in = scaled acc), += bias.
// SYNC LEDGER (free-run, proven R6/R16): per tile: {24 b128 + 4 s-ds_read ->
//  64 i8-MFMA + rescale (data-dep: all LDS reads consumed before B1)};
//  B1; stage tile t+2 (9 gloads: A4,B4,S1; S idempotent across 8 waves);
//  vmcnt(9) drains tile t+1's 9; B2 => t+1 resident cross-wave.
//  Tail: t2 clamped to t => byte-idempotent restage. Post-loop vmcnt(0).
// Swizzle (proven 0-conflict 128B-row pattern): LDS(r, 16B-seg p) =
//  G(r, seg p^(r&7)) via pre-swizzled source; read segs lk4 and 4+lk4,
//  XOR lane&7 == r&7.
// i8 frag layout (proven R16): lane(lr,lk4) reads 16B at k=16*lk4 of row lr;
//  C/D layout shape-determined (dtype-independent, m121-128).

#define WGBAR \
    __builtin_amdgcn_sched_barrier(0); \
    __builtin_amdgcn_s_barrier(); \
    __builtin_amdgcn_sched_barrier(0);

#define VMCNT(N) \
    __builtin_amdgcn_sched_barrier(0); \
    asm volatile("s_waitcnt vmcnt(" #N ")" ::: "memory"); \
    __builtin_amdgcn_sched_barrier(0);

__global__ __launch_bounds__(512, 2) void gemm_i8(const signed char* __restrict__ A,
                                                  const signed char* __restrict__ B,
                                                  const unsigned short* __restrict__ Sb,
                                                  const float* __restrict__ arow,
                                                  const unsigned short* __restrict__ zb,
                                                  const float* __restrict__ st,
                                                  const float* __restrict__ bias,
                                                  float* __restrict__ C) {
    __shared__ __align__(16) signed char sm[133120];  // 2 bufs x 66560: A 32K | B 32K | S 1K

    const int tid = threadIdx.x;
    const int w64 = tid >> 6;
    const int lane = tid & 63;

    // T1: bijective XCD swizzle (gridDim.x % 8 == 0)
    const int nwg = gridDim.x;
    const int chunk = nwg >> 3;
    const int s_id = (blockIdx.x & 7) * chunk + (blockIdx.x >> 3);
    const int nm = nwg >> 4;              // M tiles (N tiles = 16)
    const int bm = s_id % nm;
    const int bn = s_id / nm;
    const int row0 = bm * 256;
    const int col0 = bn * 256;

    const int wr = w64 >> 2;              // 0..1 (M half: 128 rows)
    const int wc = w64 & 3;               // 0..3 (N quarter: 64 cols)

    // ---- stage addressing: thread covers row tid>>3 (+64,+128h), 16B seg pre-swizzled
    const int srow = tid >> 3;
    const int sswz = 16 * ((tid & 7) ^ (srow & 7));
    const signed char* srcA = A + (size_t)(row0 + srow) * KDIM + sswz;
    const signed char* srcB = B + (size_t)(col0 + srow) * KDIM + sswz;
    const float* srcS = st + col0 + (lane << 2);       // + tile*NDIM; 16B/lane

    // ---- frag addressing (0 conflicts, proven byte math)
    const int lr = lane & 15;
    const int lk4 = lane >> 4;
    const int l7 = lane & 7;
    const int sw0 = 16 * (lk4 ^ l7);          // k 0..63 chunk
    const int sw1 = 16 * ((4 + lk4) ^ l7);    // k 64..127 chunk
    const int aBase = (wr * 128 + lr) * 128;
    const int bBase = 32768 + (wc * 64 + lr) * 128;

    f32x4 acc[8][4] = {};

    auto stageA = [&](int hh, int tile, int db) {
        const signed char* g = srcA + (size_t)hh * 128 * KDIM + (size_t)tile * 128;
        signed char* l = &sm[db * 66560 + hh * 16384 + w64 * 1024];
        gload16(g, l);
        gload16(g + (size_t)64 * KDIM, l + 8192);
    };
    auto stageB = [&](int hh, int tile, int db) {
        const signed char* g = srcB + (size_t)hh * 128 * KDIM + (size_t)tile * 128;
        signed char* l = &sm[db * 66560 + 32768 + hh * 16384 + w64 * 1024];
        gload16(g, l);
        gload16(g + (size_t)64 * KDIM, l + 8192);
    };
    auto stageS = [&](int tile, int db) {   // 1KB scale slice; all 8 waves duplicate (idempotent)
        gload16(srcS + (size_t)tile * NDIM, &sm[db * 66560 + 65536]);
    };

    const int NT = KDIM / GRP;   // 32 K-tiles; tile index == group index

    // ---- prologue: tile0 -> buf0, tile1 -> buf1 (9 gloads each)
    stageA(0, 0, 0); stageA(1, 0, 0); stageB(0, 0, 0); stageB(1, 0, 0); stageS(0, 0);
    stageA(0, 1, 1); stageA(1, 1, 1); stageB(0, 1, 1); stageB(1, 1, 1); stageS(1, 1);
    VMCNT(9)                     // tile0's 9 landed (tile1 in flight)
    WGBAR

    for (int t = 0; t < NT; ++t) {
        const int d = t & 1;
        const int dOff = d * 66560;
        const int t2 = (t + 2 < NT) ? t + 2 : t;   // clamped tail: byte-idempotent restage

        i32x4 bQ[4][2];
        float s4[4];
#pragma unroll
        for (int ni = 0; ni < 4; ++ni) {
            bQ[ni][0] = *(const i32x4*)&sm[dOff + bBase + ni * 2048 + sw0];
            bQ[ni][1] = *(const i32x4*)&sm[dOff + bBase + ni * 2048 + sw1];
        }
#pragma unroll
        for (int ni = 0; ni < 4; ++ni)
            s4[ni] = *(const float*)&sm[dOff + 65536 + (wc * 64 + ni * 16 + lr) * 4];

        __builtin_amdgcn_s_setprio(1);
#pragma unroll
        for (int mh = 0; mh < 2; ++mh) {
            i32x4 aF[4][2];
#pragma unroll
            for (int mi = 0; mi < 4; ++mi) {
                aF[mi][0] = *(const i32x4*)&sm[dOff + aBase + (mh * 4 + mi) * 2048 + sw0];
                aF[mi][1] = *(const i32x4*)&sm[dOff + aBase + (mh * 4 + mi) * 2048 + sw1];
            }
#pragma unroll
            for (int mi = 0; mi < 4; ++mi)
#pragma unroll
                for (int ni = 0; ni < 4; ++ni) {
                    i32x4 ai = __builtin_amdgcn_mfma_i32_16x16x64_i8(
                        aF[mi][0], bQ[ni][0], (i32x4){0, 0, 0, 0}, 0, 0, 0);
                    ai = __builtin_amdgcn_mfma_i32_16x16x64_i8(
                        aF[mi][1], bQ[ni][1], ai, 0, 0, 0);
#pragma unroll
                    for (int r = 0; r < 4; ++r)
                        acc[mh * 4 + mi][ni][r] += s4[ni] * (float)ai[r];
                }
        }
        __builtin_amdgcn_s_setprio(0);

        // ---- B1: all LDS reads of tile t consumed (data-dep) -> buf d free ----
        WGBAR
        stageA(0, t2, d); stageA(1, t2, d); stageB(0, t2, d); stageB(1, t2, d); stageS(t2, d);
        VMCNT(9)                 // drains tile t+1's 9 loads
        WGBAR                    // B2: tile t+1 resident cross-wave
    }

    // no LDS-DMA / dangling reads may outlive the loop
    __builtin_amdgcn_sched_barrier(0);
    asm volatile("s_waitcnt vmcnt(0) lgkmcnt(0)" ::: "memory");
    __builtin_amdgcn_sched_barrier(0);

    // ---- epilogue: acc = a_row*acc (i8 part), then z-term via bf16 MFMA (C-in), +bias
    float am[8][4];
#pragma unroll
    for (int m = 0; m < 8; ++m)
#pragma unroll
        for (int r = 0; r < 4; ++r)
            am[m][r] = arow[row0 + wr * 128 + m * 16 + lk4 * 4 + r];
#pragma unroll
    for (int m = 0; m < 8; ++m)
#pragma unroll
        for (int n = 0; n < 4; ++n)
#pragma unroll
            for (int r = 0; r < 4; ++r)
                acc[m][n][r] *= am[m][r];

    short8 aS[8], bZ[4];
#pragma unroll
    for (int m = 0; m < 8; ++m)
        aS[m] = *(const short8*)&Sb[(size_t)(row0 + wr * 128 + m * 16 + lr) * NG + lk4 * 8];
#pragma unroll
    for (int n = 0; n < 4; ++n)
        bZ[n] = *(const short8*)&zb[(size_t)(col0 + wc * 64 + n * 16 + lr) * NG + lk4 * 8];
#pragma unroll
    for (int m = 0; m < 8; ++m)
#pragma unroll
        for (int n = 0; n < 4; ++n)
            acc[m][n] = __builtin_amdgcn_mfma_f32_16x16x32_bf16(
                __builtin_bit_cast(bf16x8, aS[m]), __builtin_bit_cast(bf16x8, bZ[n]),
                acc[m][n], 0, 0, 0);

    // C/D layout col=lane&15, row=(lane>>4)*4+r (verified)
#pragma unroll
    for (int m = 0; m < 8; ++m) {
#pragma unroll
        for (int n = 0; n < 4; ++n) {
            int col = col0 + wc * 64 + n * 16 + lr;
            float bz = bias[col];
#pragma unroll
            for (int r = 0; r < 4; ++r) {
                int row = row0 + wr * 128 + m * 16 + lk4 * 4 + r;
                C[(size_t)row * NDIM + col] = acc[m][n][r] + bz;
            }
        }
    }
}

// ---------------- emergency fallback (ws too small / odd shape): exact fp32 ----------------
__global__ void fallback_kernel(const float* __restrict__ x, const int* __restrict__ wp,
                                const float* __restrict__ scales, const float* __restrict__ zeros,
                                const float* __restrict__ bias, float* __restrict__ out) {
    int o = blockIdx.x * 256 + threadIdx.x;
    int m = blockIdx.y;
    __shared__ float xs[KDIM];
    for (int i = threadIdx.x; i < KDIM; i += 256) xs[i] = x[(size_t)m * KDIM + i];
    __syncthreads();
    float acc = 0.f;
    for (int g = 0; g < 32; ++g) {
        float s = scales[o * 32 + g], z = zeros[o * 32 + g];
        float aq = 0.f, ax = 0.f;
        for (int j = 0; j < 32; ++j) {
            int p = wp[o * 1024 + g * 32 + j];
            int kb = g * 128 + j * 4;
#pragma unroll
            for (int q = 0; q < 4; ++q) {
                float xv = xs[kb + q];
                aq += xv * (float)((p >> (2 * q)) & 3);
                ax += xv;
            }
        }
        acc += s * aq + z * ax;
    }
    out[(size_t)m * NDIM + o] = acc + bias[o];
}

extern "C" void kernel_launch(void* const* d_in, const int* in_sizes, int n_in,
                              void* d_out, int out_size, void* d_ws, size_t ws_size,
                              hipStream_t stream) {
    const float* x      = (const float*)d_in[0];
    const int*   wp     = (const int*)d_in[1];
    const float* scales = (const float*)d_in[2];
    const float* zeros  = (const float*)d_in[3];
    const float* bias   = (const float*)d_in[4];
    float* out = (float*)d_out;

    const long M = (long)in_sizes[0] / KDIM;            // 8192
    const long PACKED = (long)in_sizes[1];              // 4194304

    // ws layout (bytes)
    const size_t xq_off = 0;
    const size_t wq_off = (size_t)M * KDIM;
    const size_t Sb_off = wq_off + (size_t)NDIM * KDIM;
    const size_t ar_off = Sb_off + (size_t)M * NG * 2;
    const size_t zb_off = ar_off + (size_t)M * 4;
    const size_t st_off = zb_off + (size_t)NDIM * NG * 2;
    const size_t need   = st_off + (size_t)NG * NDIM * 4;

    if (ws_size >= need && (M % 256) == 0) {
        signed char* xq = (signed char*)d_ws + xq_off;
        signed char* wq = (signed char*)d_ws + wq_off;
        unsigned short* Sb = (unsigned short*)((char*)d_ws + Sb_off);
        float* ar = (float*)((char*)d_ws + ar_off);
        unsigned short* zb = (unsigned short*)((char*)d_ws + zb_off);
        float* st = (float*)((char*)d_ws + st_off);

        int nbx = (int)M;                               // 8192 row blocks
        int nbw = (int)((NDIM * (long)KDIM / 16) / 256);// 4096 unpack blocks
        int nbz = (int)((NDIM * (long)NG) / 256);       // 512 z/st blocks
        prep_kernel<<<nbx + nbw + nbz, 256, 0, stream>>>(x, wp, scales, zeros,
                                                         xq, wq, Sb, ar, zb, st, nbx, nbw);
        int nwg = (int)(M / 256) * (NDIM / 256);        // 512, %8==0
        gemm_i8<<<nwg, 512, 0, stream>>>(xq, wq, Sb, ar, zb, st, bias, out);
    } else {
        dim3 grid(NDIM / 256, M);
        fallback_kernel<<<grid, 256, 0, stream>>>(x, wp, scales, zeros, bias, out);
    }
}